// Round 5
// baseline (335.147 us; speedup 1.0000x reference)
//
#include <hip/hip_runtime.h>
#include <cstdint>
#include <cstddef>

#define NB 32        // batch
#define NC 256       // channels
#define HW 56        // spatial
#define PLANE (HW*HW)       // 3136
#define NPLANE (NB*NC)      // 8192
#define NHEADS 8
#define HDIM 32
#define NPOOL 64            // 8*8
#define EPSV 1e-5f

// ---------------------------------------------------------------------------
// K1: row/col means. Wave-autonomous: each wave owns a 12.5 KB LDS slice and
// processes planes grid-stride with NO __syncthreads. Loads for the next plane
// overlap the LDS reduction of the current one (buf[] stays in registers).
// ---------------------------------------------------------------------------
__global__ __launch_bounds__(256) void k_means(const float* __restrict__ x,
                                               float* __restrict__ hm,
                                               float* __restrict__ wm) {
    __shared__ float sm[4][PLANE];
    const int wid = threadIdx.x >> 6, lane = threadIdx.x & 63;
    float* myL = sm[wid];
    float4* myL4 = (float4*)myL;
    const int gw = blockIdx.x * 4 + wid;       // 0..4095
    float4 buf[13];

    // prefetch first plane
    {
        const float4* pb = (const float4*)(x + (size_t)gw * PLANE);
#pragma unroll
        for (int k = 0; k < 12; ++k) buf[k] = pb[k * 64 + lane];
        if (lane < 16) buf[12] = pb[768 + lane];
    }
    for (int plane = gw; plane < NPLANE; plane += 4096) {
        // spill regs -> my LDS slice (2-way bank alias on b128: free)
#pragma unroll
        for (int k = 0; k < 12; ++k) myL4[k * 64 + lane] = buf[k];
        if (lane < 16) myL4[768 + lane] = buf[12];
        // prefetch next plane while reducing this one
        int np = plane + 4096;
        if (np < NPLANE) {
            const float4* pb = (const float4*)(x + (size_t)np * PLANE);
#pragma unroll
            for (int k = 0; k < 12; ++k) buf[k] = pb[k * 64 + lane];
            if (lane < 16) buf[12] = pb[768 + lane];
        }
        // row sums (lane = row): 14 float4 reads
        if (lane < 56) {
            float s = 0.f;
#pragma unroll
            for (int i = 0; i < 14; ++i) {
                float4 v = myL4[lane * 14 + i];
                s += (v.x + v.y) + (v.z + v.w);
            }
            hm[(size_t)plane * 56 + lane] = s * (1.f / 56.f);
            // col sums (lane = col): 56 b32 reads stride 56
            float s2 = 0.f;
#pragma unroll
            for (int r = 0; r < 56; ++r) s2 += myL[r * 56 + lane];
            wm[(size_t)plane * 56 + lane] = s2 * (1.f / 56.f);
        }
        // no barrier: only this wave touches myL; lgkmcnt ordering is automatic
    }
}

// ---------------------------------------------------------------------------
// K2: sa_branch (depthwise conv + GroupNorm(4) + sigmoid). 64 blocks. (round-2)
// ---------------------------------------------------------------------------
__global__ __launch_bounds__(256) void k_branch(
    const float* __restrict__ hm, const float* __restrict__ wm,
    const float* __restrict__ w3, const float* __restrict__ b3,
    const float* __restrict__ w5, const float* __restrict__ b5,
    const float* __restrict__ w7, const float* __restrict__ b7,
    const float* __restrict__ w9, const float* __restrict__ b9,
    const float* __restrict__ hsc, const float* __restrict__ hbi,
    const float* __restrict__ wsc, const float* __restrict__ wbi,
    float* __restrict__ hattn, float* __restrict__ wattn) {
    int mode = blockIdx.x & 1;
    int b = blockIdx.x >> 1;
    const float* src = (mode == 0 ? hm : wm) + (size_t)b * NC * 56;
    const float* scale = (mode == 0 ? hsc : wsc);
    const float* bias = (mode == 0 ? hbi : wbi);
    float* dst = (mode == 0 ? hattn : wattn) + (size_t)b * NC * 56;

    __shared__ float sm[NC * 57];
    int t = threadIdx.x;
    const float4* sp = (const float4*)src;
#pragma unroll
    for (int k = 0; k < 14; ++k) {
        int f = t + 256 * k;
        float4 v = sp[f];
        int c = f / 14, r = f - c * 14;
        float* d = &sm[c * 57 + r * 4];
        d[0] = v.x; d[1] = v.y; d[2] = v.z; d[3] = v.w;
    }
    __syncthreads();

    int c = t;
    int g = c >> 6, cc = c & 63;
    float wc[9];
#pragma unroll
    for (int i = 0; i < 9; ++i) wc[i] = 0.f;
    float bb = 0.f;
    if (g == 0) {
#pragma unroll
        for (int q = 0; q < 3; ++q) wc[3 + q] = w3[cc * 3 + q];
        bb = b3[cc];
    } else if (g == 1) {
#pragma unroll
        for (int q = 0; q < 5; ++q) wc[2 + q] = w5[cc * 5 + q];
        bb = b5[cc];
    } else if (g == 2) {
#pragma unroll
        for (int q = 0; q < 7; ++q) wc[1 + q] = w7[cc * 7 + q];
        bb = b7[cc];
    } else {
#pragma unroll
        for (int q = 0; q < 9; ++q) wc[q] = w9[cc * 9 + q];
        bb = b9[cc];
    }

    float xv[56];
#pragma unroll
    for (int i = 0; i < 56; ++i) xv[i] = sm[c * 57 + i];

    float s1 = 0.f, s2 = 0.f;
#pragma unroll
    for (int i = 0; i < 56; ++i) {
        float a = bb;
#pragma unroll
        for (int d = 0; d < 9; ++d) {
            int j = i + d - 4;
            if (j >= 0 && j < 56) a += wc[d] * xv[j];
        }
        s1 += a;
        s2 += a * a;
    }
#pragma unroll
    for (int off = 32; off >= 1; off >>= 1) {
        s1 += __shfl_xor(s1, off);
        s2 += __shfl_xor(s2, off);
    }
    float mean = s1 * (1.f / 3584.f);
    float var = s2 * (1.f / 3584.f) - mean * mean;
    float rstd = rsqrtf(var + EPSV);
    float scv = scale[c];
    float a_lin = scv * rstd;
    float b_lin = bias[c] - mean * rstd * scv;
#pragma unroll
    for (int i = 0; i < 56; ++i) {
        float a = bb;
#pragma unroll
        for (int d = 0; d < 9; ++d) {
            int j = i + d - 4;
            if (j >= 0 && j < 56) a += wc[d] * xv[j];
        }
        float v = a * a_lin + b_lin;
        sm[c * 57 + i] = 1.f / (1.f + expf(-v));
    }
    __syncthreads();
    float4* dp = (float4*)dst;
#pragma unroll
    for (int k = 0; k < 14; ++k) {
        int f = t + 256 * k;
        int c2 = f / 14, r = f - c2 * 14;
        const float* s = &sm[c2 * 57 + r * 4];
        dp[f] = make_float4(s[0], s[1], s[2], s[3]);
    }
}

// ---------------------------------------------------------------------------
// K3: gated 7x7 avgpool. Wave-autonomous, barrier-free (same scheme as K1).
// Lane (i,j) computes one pooled cell from the wave's LDS slice.
// ---------------------------------------------------------------------------
__global__ __launch_bounds__(256) void k_pool(const float* __restrict__ x,
                                              const float* __restrict__ hattn,
                                              const float* __restrict__ wattn,
                                              float* __restrict__ ypool) {
    __shared__ float sm[4][PLANE];
    __shared__ float gg[4][112];            // [0:56) ha, [56:112) wa
    const int wid = threadIdx.x >> 6, lane = threadIdx.x & 63;
    float* myL = sm[wid];
    float4* myL4 = (float4*)myL;
    float* myG = gg[wid];
    const int gw = blockIdx.x * 4 + wid;
    float4 buf[13];
    float gh, gwv;

    {
        const float4* pb = (const float4*)(x + (size_t)gw * PLANE);
#pragma unroll
        for (int k = 0; k < 12; ++k) buf[k] = pb[k * 64 + lane];
        if (lane < 16) buf[12] = pb[768 + lane];
        gh = (lane < 56) ? hattn[(size_t)gw * 56 + lane] : 0.f;
        gwv = (lane < 56) ? wattn[(size_t)gw * 56 + lane] : 0.f;
    }
    for (int plane = gw; plane < NPLANE; plane += 4096) {
#pragma unroll
        for (int k = 0; k < 12; ++k) myL4[k * 64 + lane] = buf[k];
        if (lane < 16) myL4[768 + lane] = buf[12];
        if (lane < 56) { myG[lane] = gh; myG[56 + lane] = gwv; }
        int np = plane + 4096;
        if (np < NPLANE) {
            const float4* pb = (const float4*)(x + (size_t)np * PLANE);
#pragma unroll
            for (int k = 0; k < 12; ++k) buf[k] = pb[k * 64 + lane];
            if (lane < 16) buf[12] = pb[768 + lane];
            gh = (lane < 56) ? hattn[(size_t)np * 56 + lane] : 0.f;
            gwv = (lane < 56) ? wattn[(size_t)np * 56 + lane] : 0.f;
        }
        {
            int i = lane >> 3, j = lane & 7;
            float s = 0.f;
#pragma unroll
            for (int dh = 0; dh < 7; ++dh) {
                float r = 0.f;
#pragma unroll
                for (int dw = 0; dw < 7; ++dw)
                    r += myL[(7 * i + dh) * 56 + 7 * j + dw] * myG[56 + 7 * j + dw];
                s += myG[7 * i + dh] * r;
            }
            ypool[(size_t)plane * NPOOL + lane] = s * (1.f / 49.f);
        }
    }
}

// ---------------------------------------------------------------------------
// K4: per-(b,head) attention -> channel gate ca (GN1 stats in-block). (round-2)
// ---------------------------------------------------------------------------
__global__ __launch_bounds__(64) void k_attn(const float* __restrict__ ypool,
                                             const float* __restrict__ nsc,
                                             const float* __restrict__ nbi,
                                             const float* __restrict__ qw,
                                             const float* __restrict__ kw,
                                             const float* __restrict__ vw,
                                             float* __restrict__ ca) {
    int bh = blockIdx.x;
    int b = bh >> 3, h = bh & 7;
    int l = threadIdx.x;
    const float4* bp = (const float4*)(ypool + (size_t)b * NC * NPOOL);
    float s1 = 0.f, s2 = 0.f;
#pragma unroll
    for (int k = 0; k < 64; ++k) {
        float4 v = bp[l + 64 * k];
        s1 += v.x + v.y + v.z + v.w;
        s2 += v.x * v.x + v.y * v.y + v.z * v.z + v.w * v.w;
    }
#pragma unroll
    for (int off = 32; off >= 1; off >>= 1) {
        s1 += __shfl_xor(s1, off);
        s2 += __shfl_xor(s2, off);
    }
    float mean = s1 * (1.f / (NC * NPOOL));
    float var = s2 * (1.f / (NC * NPOOL)) - mean * mean;
    float rstd = rsqrtf(var + EPSV);

    __shared__ float yn[32][65];
    __shared__ float ybar[32];
    __shared__ float G[32][33];
    const float* base = ypool + ((size_t)b * NC + h * HDIM) * NPOOL;
#pragma unroll
    for (int m = 0; m < 32; ++m) {
        int idx = l + 64 * m;
        int d = idx >> 6, p = idx & 63;
        int ch = h * HDIM + d;
        float v = base[idx];
        yn[d][p] = (v - mean) * rstd * nsc[ch] + nbi[ch];
    }
    __syncthreads();
    if (l < 32) {
        float s = 0.f;
#pragma unroll
        for (int p = 0; p < 64; ++p) s += yn[l][p];
        ybar[l] = s * (1.f / 64.f);
    }
    __syncthreads();
#pragma unroll
    for (int m = 0; m < 16; ++m) {
        int idx = l + 64 * m;
        int d = idx >> 5, e = idx & 31;
        float s = 0.f;
#pragma unroll
        for (int p = 0; p < 64; ++p) s += yn[d][p] * yn[e][p];
        G[d][e] = s;
    }
    __syncthreads();
    if (l < 32) {
        int d = l, cd = h * HDIM + d;
        float qs = qw[cd] * 0.17677669529663687f;   // 1/sqrt(32)
        float a[32];
        float mx = -1e30f;
#pragma unroll
        for (int e = 0; e < 32; ++e) {
            a[e] = G[d][e] * qs * kw[h * HDIM + e];
            mx = fmaxf(mx, a[e]);
        }
        float sum = 0.f;
#pragma unroll
        for (int e = 0; e < 32; ++e) {
            a[e] = expf(a[e] - mx);
            sum += a[e];
        }
        float o = 0.f;
#pragma unroll
        for (int e = 0; e < 32; ++e) o += a[e] * vw[h * HDIM + e] * ybar[e];
        o /= sum;
        ca[b * NC + cd] = 1.f / (1.f + expf(-o));
    }
}

// ---------------------------------------------------------------------------
// K5: out = x * hattn * wattn * ca. Wave-autonomous streaming, barrier-free.
// Gates live in the wave's tiny LDS slice; x is read straight to registers.
// ---------------------------------------------------------------------------
__global__ __launch_bounds__(256) void k_final(const float* __restrict__ x,
                                               const float* __restrict__ hattn,
                                               const float* __restrict__ wattn,
                                               const float* __restrict__ ca,
                                               float* __restrict__ out) {
    __shared__ float gg[4][128];            // [0:56) hv*ca, [64:120) wv
    const int wid = threadIdx.x >> 6, lane = threadIdx.x & 63;
    float* myG = gg[wid];
    const int gw = blockIdx.x * 4 + wid;

    for (int plane = gw; plane < NPLANE; plane += 4096) {
        if (lane < 56) {
            myG[lane] = hattn[(size_t)plane * 56 + lane] * ca[plane];
            myG[64 + lane] = wattn[(size_t)plane * 56 + lane];
        }
        // intra-wave LDS dependency: lgkmcnt wait auto-inserted; no barrier
        const float4* xp = (const float4*)(x + (size_t)plane * PLANE);
        float4* op = (float4*)(out + (size_t)plane * PLANE);
        float4 buf[13];
#pragma unroll
        for (int k = 0; k < 12; ++k) buf[k] = xp[k * 64 + lane];
        if (lane < 16) buf[12] = xp[768 + lane];
#pragma unroll
        for (int k = 0; k < 12; ++k) {
            int f = k * 64 + lane;
            int r = f / 14, s0 = (f - r * 14) * 4;
            float hf = myG[r];
            float4 v = buf[k];
            v.x *= hf * myG[64 + s0];
            v.y *= hf * myG[64 + s0 + 1];
            v.z *= hf * myG[64 + s0 + 2];
            v.w *= hf * myG[64 + s0 + 3];
            op[f] = v;
        }
        if (lane < 16) {
            int f = 768 + lane;
            int r = f / 14, s0 = (f - r * 14) * 4;
            float hf = myG[r];
            float4 v = buf[12];
            v.x *= hf * myG[64 + s0];
            v.y *= hf * myG[64 + s0 + 1];
            v.z *= hf * myG[64 + s0 + 2];
            v.w *= hf * myG[64 + s0 + 3];
            op[f] = v;
        }
    }
}

extern "C" void kernel_launch(void* const* d_in, const int* in_sizes, int n_in,
                              void* d_out, int out_size, void* d_ws, size_t ws_size,
                              hipStream_t stream) {
    const float* x   = (const float*)d_in[0];
    const float* w3  = (const float*)d_in[1];
    const float* b3  = (const float*)d_in[2];
    const float* w5  = (const float*)d_in[3];
    const float* b5  = (const float*)d_in[4];
    const float* w7  = (const float*)d_in[5];
    const float* b7  = (const float*)d_in[6];
    const float* w9  = (const float*)d_in[7];
    const float* b9  = (const float*)d_in[8];
    const float* hsc = (const float*)d_in[9];
    const float* hbi = (const float*)d_in[10];
    const float* wsc = (const float*)d_in[11];
    const float* wbi = (const float*)d_in[12];
    const float* nsc = (const float*)d_in[13];
    const float* nbi = (const float*)d_in[14];
    const float* qw  = (const float*)d_in[15];
    const float* kw  = (const float*)d_in[16];
    const float* vw  = (const float*)d_in[17];
    float* out = (float*)d_out;

    float* ws    = (float*)d_ws;
    float* hm    = ws;
    float* wm    = hm + (size_t)NPLANE * 56;
    float* hattn = wm + (size_t)NPLANE * 56;
    float* wattn = hattn + (size_t)NPLANE * 56;
    float* ypool = wattn + (size_t)NPLANE * 56;
    float* ca    = ypool + (size_t)NPLANE * NPOOL;

    k_means<<<1024, 256, 0, stream>>>(x, hm, wm);
    k_branch<<<2 * NB, 256, 0, stream>>>(hm, wm, w3, b3, w5, b5, w7, b7, w9, b9,
                                         hsc, hbi, wsc, wbi, hattn, wattn);
    k_pool<<<1024, 256, 0, stream>>>(x, hattn, wattn, ypool);
    k_attn<<<NB * NHEADS, 64, 0, stream>>>(ypool, nsc, nbi, qw, kw, vw, ca);
    k_final<<<1024, 256, 0, stream>>>(x, hattn, wattn, ca, out);
}